// Round 1
// baseline (918.130 us; speedup 1.0000x reference)
//
#include <hip/hip_runtime.h>

// out[b,s,h] = sum_{a,d} x[b,a,h,d] * K[s,a] * W[s,d]
// K is a 2-tap lerp over altitude: a0 = floor(alt_s) (clamped to [0,12]), f = alt_s - a0
// => out[b,s,h] = sum_d w0[s,d]*x[b,a0,h,d] + w1[s,d]*x[b,a0+1,h,d]
//    w0 = (1-f)*W[s,:],  w1 = f*W[s,:]
//
// B=65536, A=14, H=3, D=8, S=512. Output fp32 402.7 MB -> write-bound (~78us floor).

#define A_DIM 14
#define H_DIM 3
#define D_DIM 8
#define S_DIM 512
#define XSTR (A_DIM * H_DIM * D_DIM)   // 336 floats per batch
#define OSTR (S_DIM * H_DIM)           // 1536 floats per batch

// ---------------- spot table: {a0, w0[8], w1[8]} per spot ----------------
__global__ __launch_bounds__(S_DIM) void spot_table_kernel(
    const float* __restrict__ windWeights,  // (S, D)
    const float* __restrict__ alt,          // (S, 1)
    float* __restrict__ wtab,               // (S, 16): w0[8] || w1[8]
    int* __restrict__ a0tab)                // (S,)
{
    const int s = threadIdx.x;
    if (s >= S_DIM) return;
    const float a = alt[s];
    int a0 = (int)floorf(a);
    if (a0 < 0) a0 = 0;
    if (a0 > A_DIM - 2) a0 = A_DIM - 2;   // alt==13 -> a0=12, f=1 (matches clip form)
    const float f  = a - (float)a0;
    const float g0 = 1.0f - f;
#pragma unroll
    for (int d = 0; d < D_DIM; ++d) {
        const float w = windWeights[s * D_DIM + d];
        wtab[s * 16 + d]     = g0 * w;
        wtab[s * 16 + 8 + d] = f  * w;
    }
    a0tab[s] = a0;
}

// ---------------- main kernel ----------------
// Block = 192 threads = 3 waves; thread t -> (b_loc = t/3, h = t%3); 64 batches/block.
// x[b,:,h,:] (112 floats) lives in registers; spot weights are wave-uniform
// (scalar loads); uniform switch on a0 picks compile-time register indices.

#define DOTCASE(AA)                                          \
    case AA: {                                               \
        _Pragma("unroll")                                    \
        for (int d = 0; d < D_DIM; ++d) {                    \
            r0 = fmaf(w0[d], xr[AA][d], r0);                 \
            r1 = fmaf(w1[d], xr[AA + 1][d], r1);             \
        }                                                    \
    } break;

__global__ __launch_bounds__(192) void wind_main_kernel(
    const float* __restrict__ x,      // (B, A, H, D)
    const float* __restrict__ wtab,   // (S, 16)
    const int* __restrict__ a0tab,    // (S,)
    float* __restrict__ out,          // (B, S, H)
    int Btot)
{
    const int t = threadIdx.x;
    const int b_loc = t / 3;
    const int h = t - b_loc * 3;
    const long b = (long)blockIdx.x * 64 + b_loc;
    if (b >= Btot) return;

    // load x[b, :, h, :] into registers (fully unrolled, compile-time indices)
    const float* xp = x + b * XSTR + h * D_DIM;
    float xr[A_DIM][D_DIM];
#pragma unroll
    for (int a = 0; a < A_DIM; ++a) {
        const float4 v0 = *reinterpret_cast<const float4*>(xp + a * (H_DIM * D_DIM));
        const float4 v1 = *reinterpret_cast<const float4*>(xp + a * (H_DIM * D_DIM) + 4);
        xr[a][0] = v0.x; xr[a][1] = v0.y; xr[a][2] = v0.z; xr[a][3] = v0.w;
        xr[a][4] = v1.x; xr[a][5] = v1.y; xr[a][6] = v1.z; xr[a][7] = v1.w;
    }

    float* op = out + b * OSTR + h;

#pragma unroll 1
    for (int s = 0; s < S_DIM; ++s) {
        const int a0 = a0tab[s];  // wave-uniform -> s_load + uniform branch
        const float4* wp = reinterpret_cast<const float4*>(wtab) + (s << 2);
        const float4 wa = wp[0], wb = wp[1], wc = wp[2], wd = wp[3];
        const float w0[D_DIM] = {wa.x, wa.y, wa.z, wa.w, wb.x, wb.y, wb.z, wb.w};
        const float w1[D_DIM] = {wc.x, wc.y, wc.z, wc.w, wd.x, wd.y, wd.z, wd.w};

        float r0 = 0.0f, r1 = 0.0f;
        switch (a0) {
            DOTCASE(0)  DOTCASE(1)  DOTCASE(2)  DOTCASE(3)
            DOTCASE(4)  DOTCASE(5)  DOTCASE(6)  DOTCASE(7)
            DOTCASE(8)  DOTCASE(9)  DOTCASE(10) DOTCASE(11)
            DOTCASE(12)
        }
        op[s * H_DIM] = r0 + r1;
    }
}

extern "C" void kernel_launch(void* const* d_in, const int* in_sizes, int n_in,
                              void* d_out, int out_size, void* d_ws, size_t ws_size,
                              hipStream_t stream) {
    const float* x           = (const float*)d_in[0];
    const float* windWeights = (const float*)d_in[1];
    const float* alt         = (const float*)d_in[2];
    float* out = (float*)d_out;

    const int Btot = in_sizes[0] / XSTR;  // 65536

    float* wtab = (float*)d_ws;                          // 512*16*4 = 32 KB
    int*   a0tab = (int*)((char*)d_ws + S_DIM * 16 * 4); // 2 KB

    spot_table_kernel<<<1, S_DIM, 0, stream>>>(windWeights, alt, wtab, a0tab);

    const int blocks = (Btot + 63) / 64;
    wind_main_kernel<<<blocks, 192, 0, stream>>>(x, wtab, a0tab, out, Btot);
}

// Round 2
// 167.558 us; speedup vs baseline: 5.4795x; 5.4795x over previous
//
#include <hip/hip_runtime.h>

// out[b,s,h] = sum_{a,d} x[b,a,h,d] * K[s,a] * W[s,d]
// Reformulated as bf16 GEMM: out[(b,h), s] = X[(b,h),(a,d)] . Wm[s,(a,d)]^T
//   M = B*H = 196608, K = A*D = 112 (padded to 128 with exact zeros), N = S = 512
// Wm[s, a*8+d] = K[s,a]*W[s,d]; K[s,a] has only 2 nonzero taps, so the dense
// bf16 GEMM equals the sparse 2-tap lerp up to bf16 rounding of 16 live terms.
//
// Block tile: BM=192 rows (64 batches x 3 h) x BN=128 spots, K=128 in one pass.
// 8 waves (2 m x 4 s), wave tile 96x32, acc 6x2 frags of 16x16.
// LDS: A [192][128] bf16 (48KB) + B [128][128] bf16 (32KB) = 80KB -> 2 blocks/CU.
// Both tiles XOR-swizzled (byte ^= (row&7)<<4) to kill the 16-way ds_read_b128
// bank conflict of a 256B-stride row-major tile.

#define A_DIM 14
#define H_DIM 3
#define D_DIM 8
#define S_DIM 512
#define KP    128            // padded K (A_DIM*D_DIM = 112 -> 128)
#define XSTR  (A_DIM * H_DIM * D_DIM)   // 336 floats per batch
#define OSTR  (S_DIM * H_DIM)           // 1536 floats per batch

#define BB 64                // batches per block
#define BM 192               // m-rows per block (BB*3)
#define BN 128               // spots per block
#define B_LDS_OFF 49152      // A tile bytes = 192*256

typedef short bf16x8 __attribute__((ext_vector_type(8)));
typedef float f32x4  __attribute__((ext_vector_type(4)));

static __device__ __forceinline__ unsigned short f2bf(float f) {
    // round-to-nearest-even f32 -> bf16 (inputs are finite)
    unsigned u = __float_as_uint(f);
    u += 0x7FFFu + ((u >> 16) & 1u);
    return (unsigned short)(u >> 16);
}

// ---------- build Wm[s][k] bf16, k = a*8+d, zero-padded to KP ----------
__global__ __launch_bounds__(S_DIM) void build_wm_kernel(
    const float* __restrict__ windWeights,   // (S, D)
    const float* __restrict__ alt,           // (S, 1)
    unsigned short* __restrict__ wmg)        // (S, KP) bf16 bits
{
    const int s = threadIdx.x;
    const float av = alt[s];
    float w[D_DIM];
#pragma unroll
    for (int d = 0; d < D_DIM; ++d) w[d] = windWeights[s * D_DIM + d];
#pragma unroll
    for (int a = 0; a < A_DIM; ++a) {
        const float g  = (float)a - av;
        const float t1 = fminf(fmaxf(g + 1.0f, 0.0f), 1.0f);
        const float t0 = fminf(fmaxf(g,        0.0f), 1.0f);
        const float Ka = t1 - t0;   // exact reference clip form
#pragma unroll
        for (int d = 0; d < D_DIM; ++d)
            wmg[s * KP + a * D_DIM + d] = f2bf(Ka * w[d]);
    }
#pragma unroll
    for (int k = A_DIM * D_DIM; k < KP; ++k) wmg[s * KP + k] = 0;
}

// ---------- main GEMM ----------
__global__ __launch_bounds__(512, 4) void wind_gemm_kernel(
    const float* __restrict__ x,             // (B, A, H, D) fp32
    const unsigned short* __restrict__ wmg,  // (S, KP) bf16
    float* __restrict__ out,                 // (B, S, H) fp32
    int Btot)
{
    __shared__ uint4 lds_raw[(BM * KP * 2 + BN * KP * 2) / 16];  // 80 KB
    char* lds = (char*)lds_raw;

    const int tid  = threadIdx.x;
    const int sblk = blockIdx.x & 3;        // s fastest: 4 s-blocks share x tile
    const int mblk = blockIdx.x >> 2;
    const int b0   = mblk * BB;
    const int s0   = sblk * BN;

    // ---- stage A: x[b0..b0+63] fp32 -> bf16 LDS [m=192][k=128], swizzled ----
    const float* xg = x + (size_t)b0 * XSTR;
#pragma unroll
    for (int it = 0; it < 11; ++it) {
        const int q = tid + it * 512;        // float4 id, 84 per batch, 5376 total
        if (q < 84 * BB) {
            const int b_loc = q / 84;
            const int o   = q - b_loc * 84;
            const int of  = o * 4;           // float offset within batch (a,h,d)
            const int a   = of / 24;
            const int r24 = of - a * 24;
            const int h   = r24 >> 3;
            const int d0  = r24 & 7;         // 0 or 4
            const float4 v = *reinterpret_cast<const float4*>(xg + (size_t)b_loc * XSTR + of);
            const unsigned lo = (unsigned)f2bf(v.x) | ((unsigned)f2bf(v.y) << 16);
            const unsigned hi = (unsigned)f2bf(v.z) | ((unsigned)f2bf(v.w) << 16);
            const int m = b_loc * 3 + h;
            int byte = m * 256 + a * 16 + d0 * 2;
            byte ^= (m & 7) << 4;
            *reinterpret_cast<uint2*>(lds + byte) = make_uint2(lo, hi);
        }
    }
    // zero-pad A rows, k = 112..127 (32 B per row = 4 x u64; 768 total)
#pragma unroll
    for (int it = 0; it < 2; ++it) {
        const int q = tid + it * 512;
        if (q < BM * 4) {
            const int m = q >> 2;
            const int c = q & 3;
            int byte = m * 256 + 224 + c * 8;
            byte ^= (m & 7) << 4;
            *reinterpret_cast<uint2*>(lds + byte) = make_uint2(0u, 0u);
        }
    }
    // ---- stage B: Wm[s0..s0+127][0..127] bf16 -> LDS, swizzled ----
    {
        const char* wg = (const char*)(wmg + (size_t)s0 * KP);
#pragma unroll
        for (int it = 0; it < 4; ++it) {
            const int p    = tid + it * 512;   // 16B chunk id, 16 per row, 2048 total
            const int srow = p >> 4;
            const int kb   = (p & 15) * 16;
            const uint4 v = *reinterpret_cast<const uint4*>(wg + srow * 256 + kb);
            int byte = B_LDS_OFF + srow * 256 + kb;
            byte ^= (srow & 7) << 4;
            *reinterpret_cast<uint4*>(lds + byte) = v;
        }
    }
    __syncthreads();

    // ---- MFMA: wave (wm_, ws_) owns 96 m x 32 s ----
    const int lane = tid & 63;
    const int wid  = tid >> 6;
    const int wm_  = wid >> 2;           // 0..1
    const int ws_  = wid & 3;            // 0..3
    const int r    = lane & 15;
    const int kq   = lane >> 4;          // 0..3
    const int swz  = (r & 7) << 4;

    f32x4 acc[6][2];
#pragma unroll
    for (int i = 0; i < 6; ++i)
#pragma unroll
        for (int j = 0; j < 2; ++j) {
            f32x4 z = {0.f, 0.f, 0.f, 0.f};
            acc[i][j] = z;
        }

    const int abase = (wm_ * 96 + r) * 256 + kq * 16;
    const int bbase = B_LDS_OFF + (ws_ * 32 + r) * 256 + kq * 16;

#pragma unroll 1
    for (int ks = 0; ks < 4; ++ks) {
        bf16x8 bfrag[2];
#pragma unroll
        for (int j = 0; j < 2; ++j)
            bfrag[j] = *reinterpret_cast<bf16x8*>(lds + ((bbase + j * 16 * 256 + ks * 64) ^ swz));
        bf16x8 afrag[6];
#pragma unroll
        for (int i = 0; i < 6; ++i)
            afrag[i] = *reinterpret_cast<bf16x8*>(lds + ((abase + i * 16 * 256 + ks * 64) ^ swz));
#pragma unroll
        for (int i = 0; i < 6; ++i)
#pragma unroll
            for (int j = 0; j < 2; ++j)
                acc[i][j] = __builtin_amdgcn_mfma_f32_16x16x32_bf16(afrag[i], bfrag[j], acc[i][j], 0, 0, 0);
    }

    // ---- epilogue: C[m, s] -> out[b, s, h]; col = lane&15, row = kq*4+reg ----
    const int scol = s0 + ws_ * 32 + r;
#pragma unroll
    for (int i = 0; i < 6; ++i) {
        const int m0 = wm_ * 96 + i * 16 + kq * 4;
        int b = m0 / 3;
        int h = m0 - b * 3;
        size_t base_b = (size_t)(b0 + b) * OSTR;
#pragma unroll
        for (int reg = 0; reg < 4; ++reg) {
#pragma unroll
            for (int j = 0; j < 2; ++j) {
                const int s = scol + j * 16;
                out[base_b + (size_t)s * 3 + h] = acc[i][j][reg];
            }
            ++h;
            if (h == 3) { h = 0; base_b += OSTR; }
        }
    }
}

extern "C" void kernel_launch(void* const* d_in, const int* in_sizes, int n_in,
                              void* d_out, int out_size, void* d_ws, size_t ws_size,
                              hipStream_t stream) {
    const float* x           = (const float*)d_in[0];
    const float* windWeights = (const float*)d_in[1];
    const float* alt         = (const float*)d_in[2];
    float* out = (float*)d_out;

    const int Btot = in_sizes[0] / XSTR;     // 65536

    unsigned short* wmg = (unsigned short*)d_ws;   // S_DIM * KP * 2 = 128 KB

    build_wm_kernel<<<1, S_DIM, 0, stream>>>(windWeights, alt, wmg);

    const int mblocks = Btot / BB;                 // 1024
    wind_gemm_kernel<<<mblocks * 4, 512, 0, stream>>>(x, wmg, out, Btot);
}

// Round 3
// 126.446 us; speedup vs baseline: 7.2610x; 1.3251x over previous
//
#include <hip/hip_runtime.h>

// out[b,s,h] = sum_{a,d} x[b,a,h,d] * K[s,a] * W[s,d]
// bf16 GEMM: out[(b,h), s] = X[(b,h),(a,d)] . Wm[s,(a,d)]^T
//   M = B*H = 196608, K = 112 -> padded 128 (exact zeros), N = S = 512
//
// Round-3 structure:
//  - block = 32 batches (96 m-rows). A tile staged fp32->bf16 into swizzled LDS ONCE.
//  - loop all 4 s-blocks of 128 spots inside the block (x read exactly once).
//  - B frags read directly from global wmg (L2-resident, full-64B-line pattern).
//  - epilogue: wave-private 6KB LDS transpose -> fully coalesced float4 stores.
//  LDS = 24KB (A) + 48KB (8 x 6KB epilogue) = 72KB -> 2 blocks/CU.

#define A_DIM 14
#define H_DIM 3
#define D_DIM 8
#define S_DIM 512
#define KP    128
#define XSTR  (A_DIM * H_DIM * D_DIM)   // 336 floats per batch
#define OSTR  (S_DIM * H_DIM)           // 1536 floats per batch

#define BB 32                 // batches per block
#define BM 96                 // m rows per block
#define BN 128                // spots per s-block
#define A_LDS (BM * 256)      // 24576 B
#define EP_CHUNK 6144         // per-wave epilogue chunk: 16 batches * 32 s * 3 h * 4B
#define LDS_BYTES (A_LDS + 8 * EP_CHUNK)   // 73728 B

typedef short bf16x8 __attribute__((ext_vector_type(8)));
typedef float f32x4  __attribute__((ext_vector_type(4)));

static __device__ __forceinline__ unsigned f2bf(float f) {
    unsigned u = __float_as_uint(f);
    u += 0x7FFFu + ((u >> 16) & 1u);
    return u >> 16;
}

// ---------- build Wm[s][k] bf16, k = a*8+d, zero-padded to KP ----------
__global__ __launch_bounds__(S_DIM) void build_wm_kernel(
    const float* __restrict__ windWeights,   // (S, D)
    const float* __restrict__ alt,           // (S, 1)
    unsigned short* __restrict__ wmg)        // (S, KP) bf16 bits
{
    const int s = threadIdx.x;
    const float av = alt[s];
    float w[D_DIM];
#pragma unroll
    for (int d = 0; d < D_DIM; ++d) w[d] = windWeights[s * D_DIM + d];
#pragma unroll
    for (int a = 0; a < A_DIM; ++a) {
        const float g  = (float)a - av;
        const float t1 = fminf(fmaxf(g + 1.0f, 0.0f), 1.0f);
        const float t0 = fminf(fmaxf(g,        0.0f), 1.0f);
        const float Ka = t1 - t0;   // exact reference clip form
#pragma unroll
        for (int d = 0; d < D_DIM; ++d)
            wmg[s * KP + a * D_DIM + d] = (unsigned short)f2bf(Ka * w[d]);
    }
#pragma unroll
    for (int k = A_DIM * D_DIM; k < KP; ++k) wmg[s * KP + k] = 0;
}

// ---------- main GEMM ----------
__global__ __launch_bounds__(512, 4) void wind_gemm_kernel(
    const float* __restrict__ x,             // (B, A, H, D) fp32
    const unsigned short* __restrict__ wmg,  // (S, KP) bf16
    float* __restrict__ out)                 // (B, S, H) fp32
{
    __shared__ __align__(16) char lds[LDS_BYTES];

    const int tid = threadIdx.x;
    const int b0  = blockIdx.x * BB;

    // ---- stage A: x[b0..b0+31] fp32 -> bf16 LDS [m=96][k=128B*2], swizzled ----
    const float* xg = x + (size_t)b0 * XSTR;
#pragma unroll
    for (int it = 0; it < 6; ++it) {
        const int q = tid + it * 512;          // float4 id; 84 per batch, 2688 total
        if (q < 84 * BB) {
            const int b_loc = q / 84;
            const int o   = q - b_loc * 84;
            const int of  = o * 4;             // float offset within batch
            const int a   = of / 24;
            const int r24 = of - a * 24;
            const int h   = r24 >> 3;
            const int d0  = r24 & 7;           // 0 or 4
            const float4 v = *reinterpret_cast<const float4*>(xg + (size_t)b_loc * XSTR + of);
            const unsigned lo = f2bf(v.x) | (f2bf(v.y) << 16);
            const unsigned hi = f2bf(v.z) | (f2bf(v.w) << 16);
            const int m = b_loc * 3 + h;
            int byte = m * 256 + a * 16 + d0 * 2;
            byte ^= (m & 7) << 4;
            *reinterpret_cast<uint2*>(lds + byte) = make_uint2(lo, hi);
        }
    }
    // zero-pad k = 112..127 (32 B per row as 4 x uint2; 384 writes)
    if (tid < BM * 4) {
        const int m = tid >> 2;
        const int c = tid & 3;
        int byte = m * 256 + 224 + c * 8;
        byte ^= (m & 7) << 4;
        *reinterpret_cast<uint2*>(lds + byte) = make_uint2(0u, 0u);
    }
    __syncthreads();

    // ---- wave decomposition: 8 waves = 2 m x 4 s; wave tile 48m x 32s ----
    const int lane = tid & 63;
    const int wid  = tid >> 6;
    const int wm_  = wid >> 2;           // 0..1
    const int ws_  = wid & 3;            // 0..3
    const int r    = lane & 15;
    const int kq   = lane >> 4;          // 0..3
    const int swz  = (r & 7) << 4;
    const int r12  = r * 12;

    const int abase = (wm_ * 48 + r) * 256 + kq * 16;
    char* ep = lds + A_LDS + wid * EP_CHUNK;

#pragma unroll 1
    for (int sblk = 0; sblk < 4; ++sblk) {
        const int s0 = sblk * BN;

        // B frags direct from global (L2-hot); rows s0+ws*32+r (+j*16), k-slice kq*16+ks*64
        const char* wb = (const char*)wmg + (size_t)(s0 + ws_ * 32 + r) * 256 + kq * 16;
        bf16x8 bfr[4][2];
#pragma unroll
        for (int ks = 0; ks < 4; ++ks)
#pragma unroll
            for (int j = 0; j < 2; ++j)
                bfr[ks][j] = *reinterpret_cast<const bf16x8*>(wb + j * 16 * 256 + ks * 64);

        f32x4 acc[3][2];
#pragma unroll
        for (int i = 0; i < 3; ++i)
#pragma unroll
            for (int j = 0; j < 2; ++j) {
                f32x4 z = {0.f, 0.f, 0.f, 0.f};
                acc[i][j] = z;
            }

#pragma unroll
        for (int ks = 0; ks < 4; ++ks) {
            bf16x8 af[3];
#pragma unroll
            for (int i = 0; i < 3; ++i)
                af[i] = *reinterpret_cast<bf16x8*>(lds + ((abase + i * 16 * 256 + ks * 64) ^ swz));
#pragma unroll
            for (int i = 0; i < 3; ++i)
#pragma unroll
                for (int j = 0; j < 2; ++j)
                    acc[i][j] = __builtin_amdgcn_mfma_f32_16x16x32_bf16(af[i], bfr[ks][j], acc[i][j], 0, 0, 0);
        }

        // ---- epilogue: acc -> wave-private LDS chunk in out-layout ----
        // chunk layout: [b_in (16)][soff (32)][h (3)] floats; addr = b_in*384 + soff*12 + h*4
#pragma unroll
        for (int i = 0; i < 3; ++i) {
            const int m_in0 = i * 16 + kq * 4;   // m within wave tile (48 rows)
            int b_in = (unsigned)m_in0 / 3u;
            int h    = m_in0 - b_in * 3;
#pragma unroll
            for (int reg = 0; reg < 4; ++reg) {
                const int bh = b_in * 384 + h * 4;
                *reinterpret_cast<float*>(ep + bh + r12)       = acc[i][0][reg];
                *reinterpret_cast<float*>(ep + bh + r12 + 192) = acc[i][1][reg];
                ++h;
                if (h == 3) { h = 0; ++b_in; }
            }
        }
        asm volatile("s_waitcnt lgkmcnt(0)" ::: "memory");

        // ---- readback + fully coalesced float4 stores ----
        // wave region: batches [b0 + wm*16, +16), out floats [ (s0+ws*32)*3, +96 ) per batch
        const size_t obase = (size_t)(b0 + wm_ * 16) * OSTR + (size_t)(s0 + ws_ * 32) * 3;
#pragma unroll
        for (int t = 0; t < 6; ++t) {
            const unsigned u    = (unsigned)lane + t * 64u;  // float4 index, < 384
            const unsigned b_in = u / 24u;                   // 24 float4 per batch
            const unsigned rem  = u - b_in * 24u;
            const float4 v = *reinterpret_cast<const float4*>(ep + u * 16u);
            *reinterpret_cast<float4*>(out + obase + (size_t)b_in * OSTR + rem * 4u) = v;
        }
        asm volatile("" ::: "memory");   // keep next sblk's LDS writes after these reads
    }
}

extern "C" void kernel_launch(void* const* d_in, const int* in_sizes, int n_in,
                              void* d_out, int out_size, void* d_ws, size_t ws_size,
                              hipStream_t stream) {
    const float* x           = (const float*)d_in[0];
    const float* windWeights = (const float*)d_in[1];
    const float* alt         = (const float*)d_in[2];
    float* out = (float*)d_out;

    const int Btot = in_sizes[0] / XSTR;     // 65536

    unsigned short* wmg = (unsigned short*)d_ws;   // S_DIM * KP * 2 = 128 KB

    build_wm_kernel<<<1, S_DIM, 0, stream>>>(windWeights, alt, wmg);

    const int blocks = Btot / BB;                  // 2048
    wind_gemm_kernel<<<blocks, 512, 0, stream>>>(x, wmg, out);
}